// Round 5
// baseline (180.619 us; speedup 1.0000x reference)
//
#include <hip/hip_runtime.h>
#include <cstdint>

#define NB 64
#define NC 256
#define HW 784              // 28*28
#define NPIX (NB*HW)        // 50176
#define NELEM ((size_t)NB*NC*HW)

typedef int v4i  __attribute__((ext_vector_type(4)));
typedef int v16i __attribute__((ext_vector_type(16)));

union U16 { signed char b[16]; int4 v; };

// ---------------------------------------------------------------------------
// alpha = mean|w| per (conv, cout). One block per (conv,cout), coalesced.
// ---------------------------------------------------------------------------
__global__ __launch_bounds__(256) void alpha_k(
    const float* __restrict__ w1, const float* __restrict__ w2,
    float* __restrict__ al1, float* __restrict__ al2) {
  int blk = blockIdx.x;
  int conv = blk >> 8, cout = blk & 255;
  const float* w = (conv ? w2 : w1) + (size_t)cout * 2304;
  int t = threadIdx.x;
  float s = 0.0f;
  for (int i = t; i < 2304; i += 256) s += fabsf(w[i]);
  __shared__ float red[256];
  red[t] = s;
  __syncthreads();
  for (int st = 128; st > 0; st >>= 1) {
    if (t < st) red[t] += red[t + st];
    __syncthreads();
  }
  if (t == 0) (conv ? al2 : al1)[cout] = red[0] / 2304.0f;
}

// ---------------------------------------------------------------------------
// Pack weights into MFMA B-fragment order: Wf[tap][chunk(8)][cgroup(8)][lane(64)][16]
// value = sign(w[cout = cg*32+(lane&31)][cin = chunk*32+(lane>>5)*16+bb][tap])
// ---------------------------------------------------------------------------
__global__ __launch_bounds__(256) void wfrag_k(
    const float* __restrict__ w1, const float* __restrict__ w2,
    signed char* __restrict__ Wf1, signed char* __restrict__ Wf2) {
  int bi = blockIdx.x;            // 144 = 2 conv x 9 tap x 8 cgroup
  int conv = bi / 72, r = bi % 72, tap = r >> 3, cg = r & 7;
  const float* w = conv ? w2 : w1;
  signed char* Wf = conv ? Wf2 : Wf1;
  int t = threadIdx.x;
  for (int e = t; e < 512; e += 256) {
    int c = e >> 6, lane = e & 63;
    int cout = cg * 32 + (lane & 31);
    int cin0 = c * 32 + (lane >> 5) * 16;
    U16 u;
#pragma unroll
    for (int bb = 0; bb < 16; ++bb) {
      float v = w[((size_t)cout * 256 + cin0 + bb) * 9 + tap];
      u.b[bb] = v > 0.f ? 1 : (v < 0.f ? -1 : 0);
    }
    *(int4*)(Wf + ((((size_t)tap * 8 + c) * 8 + cg) * 64 + lane) * 16) = u.v;
  }
}

// ---------------------------------------------------------------------------
// x (NCHW f32) -> int8 signs, pixel-major [p][256]. LDS transpose, coalesced.
// ---------------------------------------------------------------------------
__global__ __launch_bounds__(256) void pack_x(
    const float* __restrict__ in, signed char* __restrict__ A) {
  __shared__ float tile[256 * 33];
  int t = threadIdx.x;
  int P0 = blockIdx.x * 32;
  int pl = t & 31, c0 = t >> 5;
  int P = P0 + pl;
  int b = P / HW, hw = P - b * HW;
  size_t base = (size_t)b * (NC * HW) + (size_t)c0 * HW + hw;
#pragma unroll
  for (int i = 0; i < 32; ++i)
    tile[(i * 8 + c0) * 33 + pl] = in[base + (size_t)i * 8 * HW];
  __syncthreads();
  int g = t >> 4, pls = t & 15;
#pragma unroll
  for (int ph = 0; ph < 2; ++ph) {
    int pp = ph * 16 + pls;
    U16 u;
#pragma unroll
    for (int bb = 0; bb < 16; ++bb) {
      float v = tile[(g * 16 + bb) * 33 + pp];
      u.b[bb] = v > 0.f ? 1 : (v < 0.f ? -1 : 0);
    }
    *(int4*)(A + (size_t)(P0 + pp) * 256 + g * 16) = u.v;
  }
}

// ---------------------------------------------------------------------------
// int8 MFMA conv 3x3 pad 1 + per-wave i32 BN-stat partials.
// Block: 128 pixels x 128 couts; each wave computes ALL 128 px x 32 couts
// (4 A-frags x 1 W-frag per chunk-iter) -> W L2 traffic halved vs 2x2 split.
// Invalid taps read a zeroed LDS row.
// ---------------------------------------------------------------------------
__global__ __launch_bounds__(256, 3) void conv_mfma(
    const signed char* __restrict__ A, const signed char* __restrict__ Wf,
    short* __restrict__ dotb,
    int* __restrict__ pd, int* __restrict__ pq) {
  __shared__ signed char As[192 * 256 + 256];
  int t = threadIdx.x;
  int lane = t & 63, wid = t >> 6;
  int mblk = blockIdx.x >> 1, nblk = blockIdx.x & 1;
  int p0 = mblk * 128;
  int khalf = lane >> 5;

  // stage halo rows p0-29 .. p0+162 with granule swizzle (key = pixel&15)
  {
    const signed char* src = A + (size_t)(p0 - 29) * 256;
#pragma unroll
    for (int i = 0; i < 12; ++i) {
      int off = i * 4096 + t * 16;
      int4 d = *(const int4*)(src + off);
      int r = off >> 8, g = (off >> 4) & 15;
      int gs = g ^ ((r + 3) & 15);      // (p0-29+r)&15 with p0%16==0
      *(int4*)(As + r * 256 + gs * 16) = d;
    }
    if (t < 16) { int4 z = {0, 0, 0, 0}; *(int4*)(As + 192 * 256 + t * 16) = z; }
  }

  // per-lane pixel geometry for the 4 M-fragments (shared by all 4 waves)
  int prow[4], hh[4], ww[4];
#pragma unroll
  for (int i = 0; i < 4; ++i) {
    int p = p0 + i * 32 + (lane & 31);
    prow[i] = p;
    int hw = p % HW;
    hh[i] = hw / 28;
    ww[i] = hw - hh[i] * 28;
  }
  __syncthreads();

  v16i acc0 = {0}, acc1 = {0}, acc2 = {0}, acc3 = {0};
  int cg = nblk * 4 + wid;          // this wave's cgroup (32 couts)
  const signed char* wlane = Wf + ((size_t)cg * 64 + lane) * 16;

  for (int ky = 0; ky < 3; ++ky) {
#pragma unroll
    for (int kx = 0; kx < 3; ++kx) {
      int tap = ky * 3 + kx;
      int dlt = (ky - 1) * 28 + (kx - 1);
      int rb[4], kk[4];
#pragma unroll
      for (int i = 0; i < 4; ++i) {
        int hp = hh[i] + ky - 1, wp = ww[i] + kx - 1;
        bool val = ((unsigned)hp < 28u) && ((unsigned)wp < 28u);
        int pr = prow[i] + dlt;
        rb[i] = val ? (pr - (p0 - 29)) * 256 : 192 * 256;
        kk[i] = val ? ((pr & 15) << 4) : 0;
      }
      const signed char* wt = wlane + (size_t)tap * 65536;
#pragma unroll
      for (int c = 0; c < 8; ++c) {
        int gl4 = (c * 2 + khalf) << 4;
        v4i a0 = *(const v4i*)(As + rb[0] + (gl4 ^ kk[0]));
        v4i a1 = *(const v4i*)(As + rb[1] + (gl4 ^ kk[1]));
        v4i a2 = *(const v4i*)(As + rb[2] + (gl4 ^ kk[2]));
        v4i a3 = *(const v4i*)(As + rb[3] + (gl4 ^ kk[3]));
        v4i w = *(const v4i*)(wt + (size_t)c * 8192);
        acc0 = __builtin_amdgcn_mfma_i32_32x32x32_i8(a0, w, acc0, 0, 0, 0);
        acc1 = __builtin_amdgcn_mfma_i32_32x32x32_i8(a1, w, acc1, 0, 0, 0);
        acc2 = __builtin_amdgcn_mfma_i32_32x32x32_i8(a2, w, acc2, 0, 0, 0);
        acc3 = __builtin_amdgcn_mfma_i32_32x32x32_i8(a3, w, acc3, 0, 0, 0);
      }
    }
  }

  // stats: per-cout partial sums of dot and dot^2 over this block's 128 rows
  int cb = nblk * 128 + wid * 32;
  int s = 0, sq = 0;
#pragma unroll
  for (int q = 0; q < 16; ++q) {
    s  += acc0[q] + acc1[q] + acc2[q] + acc3[q];
    sq += acc0[q] * acc0[q] + acc1[q] * acc1[q] +
          acc2[q] * acc2[q] + acc3[q] * acc3[q];
  }
  s += __shfl_xor(s, 32); sq += __shfl_xor(sq, 32);
  if (lane < 32) {
    pd[mblk * 256 + cb + lane] = s;
    pq[mblk * 256 + cb + lane] = sq;
  }

  // store dot int16, pixel-major [p][256]
#pragma unroll
  for (int i = 0; i < 4; ++i) {
    v16i ac = (i == 0) ? acc0 : (i == 1) ? acc1 : (i == 2) ? acc2 : acc3;
    int pr = p0 + i * 32 + 4 * khalf;
#pragma unroll
    for (int q = 0; q < 16; ++q) {
      int row = pr + (q & 3) + 8 * (q >> 2);
      dotb[(size_t)row * 256 + cb + (lane & 31)] = (short)ac[q];
    }
  }
}

// ---------------------------------------------------------------------------
// Finalize BN from i32 partials (392 rows). One block per channel.
// y = dot*0.1*alpha; scale[c] applies to raw dot; shift[c] absolute.
// ---------------------------------------------------------------------------
__global__ __launch_bounds__(256) void bn_finalize(
    const int* __restrict__ pd, const int* __restrict__ pq,
    const float* __restrict__ alpha, const float* __restrict__ gamma,
    const float* __restrict__ beta, float* __restrict__ scale,
    float* __restrict__ shift) {
  int c = blockIdx.x, t = threadIdx.x;
  long long D = 0, D2 = 0;
  for (int r = t; r < 392; r += 256) {
    D  += (long long)pd[r * 256 + c];
    D2 += (long long)pq[r * 256 + c];
  }
  __shared__ long long rd[256], rq[256];
  rd[t] = D; rq[t] = D2;
  __syncthreads();
  for (int st = 128; st > 0; st >>= 1) {
    if (t < st) { rd[t] += rd[t + st]; rq[t] += rq[t + st]; }
    __syncthreads();
  }
  if (t == 0) {
    float sc = 0.1f * alpha[c];
    const float invN = 1.0f / (float)(NB * HW);
    float md  = (float)rd[0] * invN;
    float ex2 = (float)rq[0] * invN;
    float var = sc * sc * (ex2 - md * md);
    float rs = rsqrtf(var + 1e-5f);
    float g = gamma[c];
    scale[c] = rs * g * sc;
    shift[c] = beta[c] - sc * md * rs * g;
  }
}

// ---------------------------------------------------------------------------
// BN apply + residual + PReLU + int8 sign-pack.  dot int16 pixel-major in,
// x NCHW in, a1 NCHW out, A int8 out.
// ---------------------------------------------------------------------------
__global__ __launch_bounds__(256) void bn_mid(
    const short* __restrict__ dot, const float* __restrict__ x,
    const float* __restrict__ scale, const float* __restrict__ shift,
    const float* __restrict__ pa, float* __restrict__ a1,
    signed char* __restrict__ A) {
  __shared__ short rawd[32 * 264];
  __shared__ float tile[256 * 33];
  __shared__ float ssc[256], ssh[256];
  int t = threadIdx.x;
  int P0 = blockIdx.x * 32;
  ssc[t] = scale[t]; ssh[t] = shift[t];
  float ap = pa[0];
#pragma unroll
  for (int i = 0; i < 4; ++i) {
    int idx = i * 256 + t;
    int pl = idx >> 5, g = idx & 31;
    int4 d = *(const int4*)(dot + (size_t)(P0 + pl) * 256 + g * 8);
    *(int4*)(&rawd[pl * 264 + g * 8]) = d;
  }
  __syncthreads();
  int pl = t & 31, c0 = t >> 5;
  int P = P0 + pl;
  int b = P / HW, hw = P - b * HW;
  size_t base = (size_t)b * (NC * HW) + (size_t)c0 * HW + hw;
#pragma unroll
  for (int i = 0; i < 32; ++i) {
    int c = i * 8 + c0;
    size_t addr = base + (size_t)i * 8 * HW;
    float d = (float)rawd[pl * 264 + c];
    float v = fmaf(d, ssc[c], ssh[c]) + x[addr];
    float o = v >= 0.0f ? v : ap * v;
    a1[addr] = o;
    tile[c * 33 + pl] = o;
  }
  __syncthreads();
  int g = t >> 4, pls = t & 15;
#pragma unroll
  for (int ph = 0; ph < 2; ++ph) {
    int pp = ph * 16 + pls;
    U16 u;
#pragma unroll
    for (int bb = 0; bb < 16; ++bb) {
      float v = tile[(g * 16 + bb) * 33 + pp];
      u.b[bb] = v > 0.f ? 1 : (v < 0.f ? -1 : 0);
    }
    *(int4*)(A + (size_t)(P0 + pp) * 256 + g * 16) = u.v;
  }
}

// ---------------------------------------------------------------------------
// Final: BN apply + residual + PReLU. res aliases out (in-place safe).
// ---------------------------------------------------------------------------
__global__ __launch_bounds__(256) void bn_fin_apply(
    const short* __restrict__ dot, const float* __restrict__ res,
    const float* __restrict__ scale, const float* __restrict__ shift,
    const float* __restrict__ pa, float* __restrict__ out) {
  __shared__ short rawd[32 * 264];
  __shared__ float ssc[256], ssh[256];
  int t = threadIdx.x;
  int P0 = blockIdx.x * 32;
  ssc[t] = scale[t]; ssh[t] = shift[t];
  float ap = pa[0];
#pragma unroll
  for (int i = 0; i < 4; ++i) {
    int idx = i * 256 + t;
    int pl = idx >> 5, g = idx & 31;
    int4 d = *(const int4*)(dot + (size_t)(P0 + pl) * 256 + g * 8);
    *(int4*)(&rawd[pl * 264 + g * 8]) = d;
  }
  __syncthreads();
  int pl = t & 31, c0 = t >> 5;
  int P = P0 + pl;
  int b = P / HW, hw = P - b * HW;
  size_t base = (size_t)b * (NC * HW) + (size_t)c0 * HW + hw;
#pragma unroll
  for (int i = 0; i < 32; ++i) {
    int c = i * 8 + c0;
    size_t addr = base + (size_t)i * 8 * HW;
    float d = (float)rawd[pl * 264 + c];
    float v = fmaf(d, ssc[c], ssh[c]) + res[addr];
    out[addr] = v >= 0.0f ? v : ap * v;
  }
}

// ---------------------------------------------------------------------------
extern "C" void kernel_launch(void* const* d_in, const int* in_sizes, int n_in,
                              void* d_out, int out_size, void* d_ws, size_t ws_size,
                              hipStream_t stream) {
  const float* x   = (const float*)d_in[0];
  const float* w1  = (const float*)d_in[1];
  const float* w2  = (const float*)d_in[2];
  const float* g1  = (const float*)d_in[3];
  const float* b1  = (const float*)d_in[4];
  const float* g2  = (const float*)d_in[5];
  const float* b2  = (const float*)d_in[6];
  const float* pa1 = (const float*)d_in[7];
  const float* pa2 = (const float*)d_in[8];
  float* out = (float*)d_out;

  char* ws = (char*)d_ws;
  short*       dotb = (short*)ws;       ws += (size_t)NPIX * 256 * 2;  // 25.7MB (pre-guard for A)
  signed char* Abuf = (signed char*)ws; ws += (size_t)NPIX * 256;      // 12.85MB
  signed char* Wf1  = (signed char*)ws; ws += 589824;                  // post-guard for A
  signed char* Wf2  = (signed char*)ws; ws += 589824;
  int* pd1 = (int*)ws; ws += 392 * 256 * 4;                            // 0.4MB
  int* pq1 = (int*)ws; ws += 392 * 256 * 4;
  int* pd2 = (int*)ws; ws += 392 * 256 * 4;
  int* pq2 = (int*)ws; ws += 392 * 256 * 4;
  float* alpha1 = (float*)ws; ws += 1024;
  float* alpha2 = (float*)ws; ws += 1024;
  float* scale1 = (float*)ws; ws += 1024;
  float* shift1 = (float*)ws; ws += 1024;
  float* scale2 = (float*)ws; ws += 1024;
  float* shift2 = (float*)ws; ws += 1024;

  alpha_k<<<512, 256, 0, stream>>>(w1, w2, alpha1, alpha2);
  wfrag_k<<<144, 256, 0, stream>>>(w1, w2, Wf1, Wf2);
  pack_x<<<NPIX / 32, 256, 0, stream>>>(x, Abuf);

  conv_mfma<<<784, 256, 0, stream>>>(Abuf, Wf1, dotb, pd1, pq1);
  bn_finalize<<<256, 256, 0, stream>>>(pd1, pq1, alpha1, g1, b1, scale1, shift1);
  bn_mid<<<NPIX / 32, 256, 0, stream>>>(dotb, x, scale1, shift1, pa1, out, Abuf);

  conv_mfma<<<784, 256, 0, stream>>>(Abuf, Wf2, dotb, pd2, pq2);
  bn_finalize<<<256, 256, 0, stream>>>(pd2, pq2, alpha2, g2, b2, scale2, shift2);
  bn_fin_apply<<<NPIX / 32, 256, 0, stream>>>(dotb, out, scale2, shift2, pa2, out);
}

// Round 6
// 155.170 us; speedup vs baseline: 1.1640x; 1.1640x over previous
//
#include <hip/hip_runtime.h>
#include <cstdint>

#define NB 64
#define NC 256
#define HW 784              // 28*28
#define NPIX (NB*HW)        // 50176
#define NELEM ((size_t)NB*NC*HW)

typedef int v4i  __attribute__((ext_vector_type(4)));
typedef int v16i __attribute__((ext_vector_type(16)));

union U16 { signed char b[16]; int4 v; };

// ---------------------------------------------------------------------------
// alpha = mean|w| per (conv, cout). One block per (conv,cout), coalesced.
// ---------------------------------------------------------------------------
__global__ __launch_bounds__(256) void alpha_k(
    const float* __restrict__ w1, const float* __restrict__ w2,
    float* __restrict__ al1, float* __restrict__ al2) {
  int blk = blockIdx.x;
  int conv = blk >> 8, cout = blk & 255;
  const float* w = (conv ? w2 : w1) + (size_t)cout * 2304;
  int t = threadIdx.x;
  float s = 0.0f;
  for (int i = t; i < 2304; i += 256) s += fabsf(w[i]);
  __shared__ float red[256];
  red[t] = s;
  __syncthreads();
  for (int st = 128; st > 0; st >>= 1) {
    if (t < st) red[t] += red[t + st];
    __syncthreads();
  }
  if (t == 0) (conv ? al2 : al1)[cout] = red[0] / 2304.0f;
}

// ---------------------------------------------------------------------------
// Pack weights into MFMA B-fragment order: Wf[tap][chunk(8)][cgroup(8)][lane(64)][16]
// value = sign(w[cout = cg*32+(lane&31)][cin = chunk*32+(lane>>5)*16+bb][tap])
// ---------------------------------------------------------------------------
__global__ __launch_bounds__(256) void wfrag_k(
    const float* __restrict__ w1, const float* __restrict__ w2,
    signed char* __restrict__ Wf1, signed char* __restrict__ Wf2) {
  int bi = blockIdx.x;            // 144 = 2 conv x 9 tap x 8 cgroup
  int conv = bi / 72, r = bi % 72, tap = r >> 3, cg = r & 7;
  const float* w = conv ? w2 : w1;
  signed char* Wf = conv ? Wf2 : Wf1;
  int t = threadIdx.x;
  for (int e = t; e < 512; e += 256) {
    int c = e >> 6, lane = e & 63;
    int cout = cg * 32 + (lane & 31);
    int cin0 = c * 32 + (lane >> 5) * 16;
    U16 u;
#pragma unroll
    for (int bb = 0; bb < 16; ++bb) {
      float v = w[((size_t)cout * 256 + cin0 + bb) * 9 + tap];
      u.b[bb] = v > 0.f ? 1 : (v < 0.f ? -1 : 0);
    }
    *(int4*)(Wf + ((((size_t)tap * 8 + c) * 8 + cg) * 64 + lane) * 16) = u.v;
  }
}

// ---------------------------------------------------------------------------
// x (NCHW f32) -> int8 signs, pixel-major [p][256]. LDS transpose, coalesced.
// ---------------------------------------------------------------------------
__global__ __launch_bounds__(256) void pack_x(
    const float* __restrict__ in, signed char* __restrict__ A) {
  __shared__ float tile[256 * 33];
  int t = threadIdx.x;
  int P0 = blockIdx.x * 32;
  int pl = t & 31, c0 = t >> 5;
  int P = P0 + pl;
  int b = P / HW, hw = P - b * HW;
  size_t base = (size_t)b * (NC * HW) + (size_t)c0 * HW + hw;
#pragma unroll
  for (int i = 0; i < 32; ++i)
    tile[(i * 8 + c0) * 33 + pl] = in[base + (size_t)i * 8 * HW];
  __syncthreads();
  int g = t >> 4, pls = t & 15;
#pragma unroll
  for (int ph = 0; ph < 2; ++ph) {
    int pp = ph * 16 + pls;
    U16 u;
#pragma unroll
    for (int bb = 0; bb < 16; ++bb) {
      float v = tile[(g * 16 + bb) * 33 + pp];
      u.b[bb] = v > 0.f ? 1 : (v < 0.f ? -1 : 0);
    }
    *(int4*)(A + (size_t)(P0 + pp) * 256 + g * 16) = u.v;
  }
}

// ---------------------------------------------------------------------------
// int8 MFMA conv 3x3 pad 1 + per-wave i32 BN-stat partials.
// Block: 128 pixels x 256 couts, 4 waves; wave = 128 px x 64 co.
// Per iter: 4 A ds_reads + 2 W L2 loads -> 8 MFMAs, with explicit 1-deep
// software pipeline (ping-pong register buffers, sched_barrier-pinned).
// Invalid taps read a zeroed LDS row.
// ---------------------------------------------------------------------------
__global__ __launch_bounds__(256, 2) void conv_mfma(
    const signed char* __restrict__ A, const signed char* __restrict__ Wf,
    short* __restrict__ dotb,
    int* __restrict__ pd, int* __restrict__ pq) {
  __shared__ signed char As[192 * 256 + 256];
  int t = threadIdx.x;
  int lane = t & 63, wid = t >> 6;
  int mblk = blockIdx.x;
  int p0 = mblk * 128;
  int khalf = lane >> 5;

  // stage halo rows p0-29 .. p0+162 with granule swizzle (key = pixel&15)
  {
    const signed char* src = A + (size_t)(p0 - 29) * 256;
#pragma unroll
    for (int i = 0; i < 12; ++i) {
      int off = i * 4096 + t * 16;
      int4 d = *(const int4*)(src + off);
      int r = off >> 8, g = (off >> 4) & 15;
      int gs = g ^ ((r + 3) & 15);      // (p0-29+r)&15 with p0%16==0
      *(int4*)(As + r * 256 + gs * 16) = d;
    }
    if (t < 16) { int4 z = {0, 0, 0, 0}; *(int4*)(As + 192 * 256 + t * 16) = z; }
  }

  // per-lane pixel geometry for the 4 M-fragments (shared by all 4 waves)
  int prow[4], hh[4], ww[4];
#pragma unroll
  for (int i = 0; i < 4; ++i) {
    int p = p0 + i * 32 + (lane & 31);
    prow[i] = p;
    int hw = p % HW;
    hh[i] = hw / 28;
    ww[i] = hw - hh[i] * 28;
  }
  __syncthreads();

  v16i acc[4][2];
#pragma unroll
  for (int i = 0; i < 4; ++i) {
    v16i z = {0};
    acc[i][0] = z; acc[i][1] = z;
  }

  const signed char* wlane = Wf + ((size_t)(wid * 2) * 64 + lane) * 16;

  int rbT[2][4], kkT[2][4];
  // tap tables for tap 0 (ky=0, kx=0)
#pragma unroll
  for (int i = 0; i < 4; ++i) {
    int hp = hh[i] - 1, wp = ww[i] - 1;
    bool val = ((unsigned)hp < 28u) && ((unsigned)wp < 28u);
    int pr = prow[i] - 29;
    rbT[0][i] = val ? (pr - (p0 - 29)) * 256 : 192 * 256;
    kkT[0][i] = val ? ((pr & 15) << 4) : 0;
  }

  v4i ab[2][4], wb[2][2];
  // prologue: load iter 0 (tap 0, chunk 0)
#pragma unroll
  for (int i = 0; i < 4; ++i)
    ab[0][i] = *(const v4i*)(As + rbT[0][i] + ((khalf << 4) ^ kkT[0][i]));
  wb[0][0] = *(const v4i*)(wlane);
  wb[0][1] = *(const v4i*)(wlane + 1024);

#pragma unroll
  for (int it = 0; it < 72; ++it) {
    const int cur = it & 1, nxt = cur ^ 1;
    const int tp = it >> 3, c = it & 7;

    // at end of a tap, compute next tap's address tables
    if (c == 7 && tp < 8) {
      const int tn = tp + 1;
      const int ky = tn / 3, kx = tn % 3;
      const int dlt = (ky - 1) * 28 + (kx - 1);
#pragma unroll
      for (int i = 0; i < 4; ++i) {
        int hp = hh[i] + ky - 1, wp = ww[i] + kx - 1;
        bool val = ((unsigned)hp < 28u) && ((unsigned)wp < 28u);
        int pr = prow[i] + dlt;
        rbT[tn & 1][i] = val ? (pr - (p0 - 29)) * 256 : 192 * 256;
        kkT[tn & 1][i] = val ? ((pr & 15) << 4) : 0;
      }
    }

    // prefetch iter it+1 into the other buffer
    if (it < 71) {
      const int it1 = it + 1;
      const int t1 = it1 >> 3, c1 = it1 & 7;
      const int ts = t1 & 1;
#pragma unroll
      for (int i = 0; i < 4; ++i)
        ab[nxt][i] = *(const v4i*)(
            As + rbT[ts][i] + ((((c1 * 2 + khalf)) << 4) ^ kkT[ts][i]));
      const signed char* wt = wlane + (size_t)it1 * 8192;
      wb[nxt][0] = *(const v4i*)(wt);
      wb[nxt][1] = *(const v4i*)(wt + 1024);
    }
    __builtin_amdgcn_sched_barrier(0);

    // compute iter it
#pragma unroll
    for (int i = 0; i < 4; ++i) {
      acc[i][0] = __builtin_amdgcn_mfma_i32_32x32x32_i8(ab[cur][i], wb[cur][0],
                                                        acc[i][0], 0, 0, 0);
      acc[i][1] = __builtin_amdgcn_mfma_i32_32x32x32_i8(ab[cur][i], wb[cur][1],
                                                        acc[i][1], 0, 0, 0);
    }
  }

  // stats: per-cout partial sums of dot and dot^2 over this block's 128 rows
#pragma unroll
  for (int j = 0; j < 2; ++j) {
    int s = 0, sq = 0;
#pragma unroll
    for (int i = 0; i < 4; ++i)
#pragma unroll
      for (int q = 0; q < 16; ++q) {
        int v = acc[i][j][q];
        s += v; sq += v * v;
      }
    s += __shfl_xor(s, 32); sq += __shfl_xor(sq, 32);
    if (lane < 32) {
      pd[mblk * 256 + wid * 64 + j * 32 + lane] = s;
      pq[mblk * 256 + wid * 64 + j * 32 + lane] = sq;
    }
  }

  // store dot int16, pixel-major [p][256]
#pragma unroll
  for (int i = 0; i < 4; ++i) {
    int pr = p0 + i * 32 + 4 * khalf;
#pragma unroll
    for (int j = 0; j < 2; ++j) {
      int cb = wid * 64 + j * 32;
#pragma unroll
      for (int q = 0; q < 16; ++q) {
        int row = pr + (q & 3) + 8 * (q >> 2);
        dotb[(size_t)row * 256 + cb + (lane & 31)] = (short)acc[i][j][q];
      }
    }
  }
}

// ---------------------------------------------------------------------------
// Finalize BN from i32 partials (392 rows). One block per channel.
// y = dot*0.1*alpha; scale[c] applies to raw dot; shift[c] absolute.
// ---------------------------------------------------------------------------
__global__ __launch_bounds__(256) void bn_finalize(
    const int* __restrict__ pd, const int* __restrict__ pq,
    const float* __restrict__ alpha, const float* __restrict__ gamma,
    const float* __restrict__ beta, float* __restrict__ scale,
    float* __restrict__ shift) {
  int c = blockIdx.x, t = threadIdx.x;
  long long D = 0, D2 = 0;
  for (int r = t; r < 392; r += 256) {
    D  += (long long)pd[r * 256 + c];
    D2 += (long long)pq[r * 256 + c];
  }
  __shared__ long long rd[256], rq[256];
  rd[t] = D; rq[t] = D2;
  __syncthreads();
  for (int st = 128; st > 0; st >>= 1) {
    if (t < st) { rd[t] += rd[t + st]; rq[t] += rq[t + st]; }
    __syncthreads();
  }
  if (t == 0) {
    float sc = 0.1f * alpha[c];
    const float invN = 1.0f / (float)(NB * HW);
    float md  = (float)rd[0] * invN;
    float ex2 = (float)rq[0] * invN;
    float var = sc * sc * (ex2 - md * md);
    float rs = rsqrtf(var + 1e-5f);
    float g = gamma[c];
    scale[c] = rs * g * sc;
    shift[c] = beta[c] - sc * md * rs * g;
  }
}

// ---------------------------------------------------------------------------
// BN apply + residual + PReLU + int8 sign-pack.  dot int16 pixel-major in,
// x NCHW in, a1 NCHW out, A int8 out.
// ---------------------------------------------------------------------------
__global__ __launch_bounds__(256) void bn_mid(
    const short* __restrict__ dot, const float* __restrict__ x,
    const float* __restrict__ scale, const float* __restrict__ shift,
    const float* __restrict__ pa, float* __restrict__ a1,
    signed char* __restrict__ A) {
  __shared__ short rawd[32 * 264];
  __shared__ float tile[256 * 33];
  __shared__ float ssc[256], ssh[256];
  int t = threadIdx.x;
  int P0 = blockIdx.x * 32;
  ssc[t] = scale[t]; ssh[t] = shift[t];
  float ap = pa[0];
#pragma unroll
  for (int i = 0; i < 4; ++i) {
    int idx = i * 256 + t;
    int pl = idx >> 5, g = idx & 31;
    int4 d = *(const int4*)(dot + (size_t)(P0 + pl) * 256 + g * 8);
    *(int4*)(&rawd[pl * 264 + g * 8]) = d;
  }
  __syncthreads();
  int pl = t & 31, c0 = t >> 5;
  int P = P0 + pl;
  int b = P / HW, hw = P - b * HW;
  size_t base = (size_t)b * (NC * HW) + (size_t)c0 * HW + hw;
#pragma unroll
  for (int i = 0; i < 32; ++i) {
    int c = i * 8 + c0;
    size_t addr = base + (size_t)i * 8 * HW;
    float d = (float)rawd[pl * 264 + c];
    float v = fmaf(d, ssc[c], ssh[c]) + x[addr];
    float o = v >= 0.0f ? v : ap * v;
    a1[addr] = o;
    tile[c * 33 + pl] = o;
  }
  __syncthreads();
  int g = t >> 4, pls = t & 15;
#pragma unroll
  for (int ph = 0; ph < 2; ++ph) {
    int pp = ph * 16 + pls;
    U16 u;
#pragma unroll
    for (int bb = 0; bb < 16; ++bb) {
      float v = tile[(g * 16 + bb) * 33 + pp];
      u.b[bb] = v > 0.f ? 1 : (v < 0.f ? -1 : 0);
    }
    *(int4*)(A + (size_t)(P0 + pp) * 256 + g * 16) = u.v;
  }
}

// ---------------------------------------------------------------------------
// Final: BN apply + residual + PReLU. res aliases out (in-place safe).
// ---------------------------------------------------------------------------
__global__ __launch_bounds__(256) void bn_fin_apply(
    const short* __restrict__ dot, const float* __restrict__ res,
    const float* __restrict__ scale, const float* __restrict__ shift,
    const float* __restrict__ pa, float* __restrict__ out) {
  __shared__ short rawd[32 * 264];
  __shared__ float ssc[256], ssh[256];
  int t = threadIdx.x;
  int P0 = blockIdx.x * 32;
  ssc[t] = scale[t]; ssh[t] = shift[t];
  float ap = pa[0];
#pragma unroll
  for (int i = 0; i < 4; ++i) {
    int idx = i * 256 + t;
    int pl = idx >> 5, g = idx & 31;
    int4 d = *(const int4*)(dot + (size_t)(P0 + pl) * 256 + g * 8);
    *(int4*)(&rawd[pl * 264 + g * 8]) = d;
  }
  __syncthreads();
  int pl = t & 31, c0 = t >> 5;
  int P = P0 + pl;
  int b = P / HW, hw = P - b * HW;
  size_t base = (size_t)b * (NC * HW) + (size_t)c0 * HW + hw;
#pragma unroll
  for (int i = 0; i < 32; ++i) {
    int c = i * 8 + c0;
    size_t addr = base + (size_t)i * 8 * HW;
    float d = (float)rawd[pl * 264 + c];
    float v = fmaf(d, ssc[c], ssh[c]) + res[addr];
    out[addr] = v >= 0.0f ? v : ap * v;
  }
}

// ---------------------------------------------------------------------------
extern "C" void kernel_launch(void* const* d_in, const int* in_sizes, int n_in,
                              void* d_out, int out_size, void* d_ws, size_t ws_size,
                              hipStream_t stream) {
  const float* x   = (const float*)d_in[0];
  const float* w1  = (const float*)d_in[1];
  const float* w2  = (const float*)d_in[2];
  const float* g1  = (const float*)d_in[3];
  const float* b1  = (const float*)d_in[4];
  const float* g2  = (const float*)d_in[5];
  const float* b2  = (const float*)d_in[6];
  const float* pa1 = (const float*)d_in[7];
  const float* pa2 = (const float*)d_in[8];
  float* out = (float*)d_out;

  char* ws = (char*)d_ws;
  short*       dotb = (short*)ws;       ws += (size_t)NPIX * 256 * 2;  // 25.7MB (pre-guard for A)
  signed char* Abuf = (signed char*)ws; ws += (size_t)NPIX * 256;      // 12.85MB
  signed char* Wf1  = (signed char*)ws; ws += 589824;                  // post-guard for A
  signed char* Wf2  = (signed char*)ws; ws += 589824;
  int* pd1 = (int*)ws; ws += 392 * 256 * 4;                            // 0.4MB
  int* pq1 = (int*)ws; ws += 392 * 256 * 4;
  int* pd2 = (int*)ws; ws += 392 * 256 * 4;
  int* pq2 = (int*)ws; ws += 392 * 256 * 4;
  float* alpha1 = (float*)ws; ws += 1024;
  float* alpha2 = (float*)ws; ws += 1024;
  float* scale1 = (float*)ws; ws += 1024;
  float* shift1 = (float*)ws; ws += 1024;
  float* scale2 = (float*)ws; ws += 1024;
  float* shift2 = (float*)ws; ws += 1024;

  alpha_k<<<512, 256, 0, stream>>>(w1, w2, alpha1, alpha2);
  wfrag_k<<<144, 256, 0, stream>>>(w1, w2, Wf1, Wf2);
  pack_x<<<NPIX / 32, 256, 0, stream>>>(x, Abuf);

  conv_mfma<<<392, 256, 0, stream>>>(Abuf, Wf1, dotb, pd1, pq1);
  bn_finalize<<<256, 256, 0, stream>>>(pd1, pq1, alpha1, g1, b1, scale1, shift1);
  bn_mid<<<NPIX / 32, 256, 0, stream>>>(dotb, x, scale1, shift1, pa1, out, Abuf);

  conv_mfma<<<392, 256, 0, stream>>>(Abuf, Wf2, dotb, pd2, pq2);
  bn_finalize<<<256, 256, 0, stream>>>(pd2, pq2, alpha2, g2, b2, scale2, shift2);
  bn_fin_apply<<<NPIX / 32, 256, 0, stream>>>(dotb, out, scale2, shift2, pa2, out);
}